// Round 6
// baseline (2193.960 us; speedup 1.0000x reference)
//
#include <hip/hip_runtime.h>
#include <hip/hip_fp16.h>

#define NN 20000
#define NE 100000
#define TSQ_NB 256

typedef _Float16 f16x8 __attribute__((ext_vector_type(8)));
typedef float f32x4 __attribute__((ext_vector_type(4)));

__device__ __forceinline__ float wred(float v) {
#pragma unroll
  for (int k = 1; k < 64; k <<= 1) v += __shfl_xor(v, k);
  return v;
}

__global__ void zerok(float* __restrict__ p, int n) {
  int i = blockIdx.x * 256 + threadIdx.x;
  if (i < n) p[i] = 0.f;
}

// ---- per-column sum / sumsq over [R, C] fp32 ----
template <int C>
__global__ void colstats(const float* __restrict__ x, float* __restrict__ stat, int total) {
  __shared__ float ls[2 * C];
  for (int i = threadIdx.x; i < 2 * C; i += blockDim.x) ls[i] = 0.f;
  __syncthreads();
  for (int idx = blockIdx.x * blockDim.x + threadIdx.x; idx < total; idx += gridDim.x * blockDim.x) {
    float v = x[idx];
    int c = idx % C;
    atomicAdd(&ls[c], v);
    atomicAdd(&ls[C + c], v * v);
  }
  __syncthreads();
  for (int i = threadIdx.x; i < 2 * C; i += blockDim.x) atomicAdd(&stat[i], ls[i]);
}

__global__ void finalize_bn(const float* __restrict__ stat, const float* __restrict__ g,
                            const float* __restrict__ b, float* __restrict__ s_out,
                            float* __restrict__ c_out, int C, float invR) {
  int c = blockIdx.x * blockDim.x + threadIdx.x;
  if (c >= C) return;
  float mean = stat[c] * invR;
  float var = fmaxf(stat[C + c] * invR - mean * mean, 0.f);
  float sc = g[c] * rsqrtf(var + 1e-5f);
  s_out[c] = sc;
  c_out[c] = b[c] - mean * sc;
}

__global__ void deg_kernel(const int* __restrict__ dst, float* __restrict__ deg, int E) {
  int e = blockIdx.x * blockDim.x + threadIdx.x;
  if (e < E) atomicAdd(&deg[dst[e]], 1.f);
}

__global__ void invden_kernel(const float* __restrict__ deg, float* __restrict__ inv, int N) {
  int n = blockIdx.x * blockDim.x + threadIdx.x;
  if (n < N) inv[n] = 1.f / fmaxf(deg[n], 1.f);
}

// ---- Wc[10,128] = edge_W @ en_W1 ; bc[128] = edge_b @ en_W1 + en_b1 ----
__global__ void fold_w1(const float* __restrict__ edge_W, const float* __restrict__ edge_b,
                        const float* __restrict__ en_W1, const float* __restrict__ en_b1,
                        float* __restrict__ Wc, float* __restrict__ bc) {
  int t = threadIdx.x;
  for (int idx = t; idx < 1280; idx += 256) {
    int bq = idx >> 7, j = idx & 127;
    float a = 0.f;
    for (int q = 0; q < 128; ++q) a += edge_W[bq * 128 + q] * en_W1[q * 128 + j];
    Wc[idx] = a;
  }
  if (t < 128) {
    float a = en_b1[t];
    for (int q = 0; q < 128; ++q) a += edge_b[q] * en_W1[q * 128 + t];
    bc[t] = a;
  }
}

// ---- Sx[10][10] + xsum[10] over xb = x*es+ec ----
__global__ __launch_bounds__(64) void sx_kernel(const float* __restrict__ x,
                                                const float* __restrict__ es,
                                                const float* __restrict__ ec,
                                                float* __restrict__ sxs, int E) {
  float s[10][10], xs[10], esl[10], ecl[10];
#pragma unroll
  for (int a = 0; a < 10; ++a) {
    xs[a] = 0.f; esl[a] = es[a]; ecl[a] = ec[a];
#pragma unroll
    for (int b = 0; b < 10; ++b) s[a][b] = 0.f;
  }
  for (int e = blockIdx.x * 64 + threadIdx.x; e < E; e += gridDim.x * 64) {
    float xb[10];
#pragma unroll
    for (int q = 0; q < 10; ++q) xb[q] = x[(size_t)e * 10 + q] * esl[q] + ecl[q];
#pragma unroll
    for (int a = 0; a < 10; ++a) {
      xs[a] += xb[a];
#pragma unroll
      for (int b = 0; b < 10; ++b) s[a][b] += xb[a] * xb[b];
    }
  }
#pragma unroll
  for (int a = 0; a < 10; ++a) {
    float r = wred(xs[a]);
    if (threadIdx.x == 0) atomicAdd(&sxs[100 + a], r);
#pragma unroll
    for (int b = 0; b < 10; ++b) {
      float r2 = wred(s[a][b]);
      if (threadIdx.x == 0) atomicAdd(&sxs[a * 10 + b], r2);
    }
  }
}

// ---- BN1 scale/shift from Sx quadratic form ----
__global__ void bn1_from_sx(const float* __restrict__ sxs, const float* __restrict__ Wc,
                            const float* __restrict__ bc, const float* __restrict__ g,
                            const float* __restrict__ b, float* __restrict__ s1,
                            float* __restrict__ c1) {
  int j = threadIdx.x;  // 128
  float w[10];
#pragma unroll
  for (int q = 0; q < 10; ++q) w[q] = Wc[q * 128 + j];
  float d = 0.f;
#pragma unroll
  for (int q = 0; q < 10; ++q) d += sxs[100 + q] * w[q];
  float qq = 0.f;
#pragma unroll
  for (int a = 0; a < 10; ++a) {
    float p = 0.f;
#pragma unroll
    for (int bq = 0; bq < 10; ++bq) p += sxs[a * 10 + bq] * w[bq];
    qq += w[a] * p;
  }
  float invE = 1.f / (float)NE;
  float bias = bc[j];
  float mean = d * invE + bias;
  float m2 = (qq + 2.f * bias * d) * invE + bias * bias;
  float var = fmaxf(m2 - mean * mean, 0.f);
  float sc = g[j] * rsqrtf(var + 1e-5f);
  s1[j] = sc;
  c1[j] = b[j] - mean * sc;
}

// ---- t[e,j] = leaky(bn1(xb@Wc + bc)) -> fp16 [NE,128]; 16 rows/block ----
__global__ __launch_bounds__(256) void t_kernel(const float* __restrict__ x,
                                                const float* __restrict__ es,
                                                const float* __restrict__ ec,
                                                const float* __restrict__ Wc,
                                                const float* __restrict__ bcb,
                                                const float* __restrict__ s1,
                                                const float* __restrict__ c1,
                                                __half* __restrict__ T, int E) {
  __shared__ float Wcl[1280], bcl[128], s1l[128], c1l[128], esl[10], ecl[10];
  __shared__ float xr[16][10];
  int t = threadIdx.x;
  for (int i = t; i < 1280; i += 256) Wcl[i] = Wc[i];
  if (t < 128) { bcl[t] = bcb[t]; s1l[t] = s1[t]; c1l[t] = c1[t]; }
  if (t < 10) { esl[t] = es[t]; ecl[t] = ec[t]; }
  int r0 = blockIdx.x * 16;
  if (t < 160) xr[t / 10][t % 10] = x[(size_t)r0 * 10 + t];
  __syncthreads();
  int rl = t >> 4, c0 = (t & 15) * 8;
  float acc[8];
#pragma unroll
  for (int j = 0; j < 8; ++j) acc[j] = bcl[c0 + j];
#pragma unroll
  for (int q = 0; q < 10; ++q) {
    float xb = xr[rl][q] * esl[q] + ecl[q];
#pragma unroll
    for (int j = 0; j < 8; ++j) acc[j] += xb * Wcl[q * 128 + c0 + j];
  }
  f16x8 o;
#pragma unroll
  for (int j = 0; j < 8; ++j) {
    float tv = acc[j] * s1l[c0 + j] + c1l[c0 + j];
    tv = tv > 0.f ? tv : 0.8f * tv;
    o[j] = (_Float16)tv;
  }
  *(f16x8*)&T[(size_t)(r0 + rl) * 128 + c0] = o;
}

// ---- tsum[128] = column sum of T ----
__global__ __launch_bounds__(256) void colsum_t(const __half* __restrict__ T,
                                                float* __restrict__ tsum, int E) {
  __shared__ float cs[128];
  int t = threadIdx.x;
  int col = t & 127, hf = t >> 7;
  float a = 0.f;
  for (int r = blockIdx.x * 2 + hf; r < E; r += gridDim.x * 2)
    a += __half2float(T[(size_t)r * 128 + col]);
  if (hf) cs[col] = a;
  __syncthreads();
  if (!hf) atomicAdd(&tsum[col], a + cs[col]);
}

// ---- MFMA S = T^T @ T: per-block 128x128 fp32 partial ----
__global__ __launch_bounds__(256) void tsq_mfma(const __half* __restrict__ T,
                                                float* __restrict__ partial, int E) {
  __shared__ _Float16 tl[32 * 132];
  int t = threadIdx.x;
  int w = t >> 6, lane = t & 63;
  int g = lane >> 4, cl = lane & 15;
  f32x4 acc[2][8];
#pragma unroll
  for (int i = 0; i < 2; ++i)
#pragma unroll
    for (int j = 0; j < 8; ++j) acc[i][j] = {0.f, 0.f, 0.f, 0.f};
  int nch = E >> 5;
  for (int ch = blockIdx.x; ch < nch; ch += gridDim.x) {
    __syncthreads();
#pragma unroll
    for (int p = 0; p < 4; ++p) {
      int u = p * 256 + t;
      int e = u >> 5, c0 = (u & 31) * 4;
      *(uint2*)&tl[e * 132 + c0] = *(const uint2*)&T[((size_t)ch * 32 + e) * 128 + c0];
    }
    __syncthreads();
    f16x8 fr[8];
#pragma unroll
    for (int cb = 0; cb < 8; ++cb) {
      f16x8 f;
#pragma unroll
      for (int j = 0; j < 8; ++j) f[j] = tl[(g * 8 + j) * 132 + cb * 16 + cl];
      fr[cb] = f;
    }
    f16x8 afr[2];
#pragma unroll
    for (int ri = 0; ri < 2; ++ri) {
      int cb = w * 2 + ri;
      f16x8 f;
#pragma unroll
      for (int j = 0; j < 8; ++j) f[j] = tl[(g * 8 + j) * 132 + cb * 16 + cl];
      afr[ri] = f;
    }
#pragma unroll
    for (int ri = 0; ri < 2; ++ri)
#pragma unroll
      for (int ci = 0; ci < 8; ++ci)
        acc[ri][ci] = __builtin_amdgcn_mfma_f32_16x16x32_f16(afr[ri], fr[ci], acc[ri][ci], 0, 0, 0);
  }
  float* pb = partial + (size_t)blockIdx.x * 16384;
#pragma unroll
  for (int ri = 0; ri < 2; ++ri)
#pragma unroll
    for (int ci = 0; ci < 8; ++ci)
#pragma unroll
      for (int q = 0; q < 4; ++q)
        pb[(w * 32 + ri * 16 + g * 4 + q) * 128 + ci * 16 + cl] = acc[ri][ci][q];
}

__global__ void tsq_reduce(const float* __restrict__ partial, float* __restrict__ S) {
  int i = blockIdx.x * 256 + threadIdx.x;  // 16384
  float a = 0.f;
  for (int b = 0; b < TSQ_NB; ++b) a += partial[(size_t)b * 16384 + i];
  S[i] = a;
}

// ---- parallel BN2 from S quadratic form ----
__global__ __launch_bounds__(256) void bn2p(const float* __restrict__ S,
                                            const float* __restrict__ tsum,
                                            const float* __restrict__ W2,
                                            const float* __restrict__ b2,
                                            const float* __restrict__ g,
                                            const float* __restrict__ b,
                                            float* __restrict__ s2, float* __restrict__ c2p) {
  __shared__ float Sl[16384];
  __shared__ float tsl[128];
  for (int i = threadIdx.x; i < 16384; i += 256) Sl[i] = S[i];
  if (threadIdx.x < 128) tsl[threadIdx.x] = tsum[threadIdx.x];
  __syncthreads();
  int w = threadIdx.x >> 6, lane = threadIdx.x & 63;
  int io = blockIdx.x * 4 + w;
  float wlo = W2[(size_t)lane * 1024 + io];
  float whi = W2[(size_t)(lane + 64) * 1024 + io];
  float plo = 0.f, phi = 0.f;
#pragma unroll
  for (int a = 0; a < 64; ++a) {
    float wa = __shfl(wlo, a);
    plo += wa * Sl[a * 128 + lane];
    phi += wa * Sl[a * 128 + lane + 64];
  }
#pragma unroll
  for (int a = 0; a < 64; ++a) {
    float wa = __shfl(whi, a);
    plo += wa * Sl[(a + 64) * 128 + lane];
    phi += wa * Sl[(a + 64) * 128 + lane + 64];
  }
  float qq = wred(plo * wlo + phi * whi);
  float d = wred(wlo * tsl[lane] + whi * tsl[lane + 64]);
  if (lane == 0) {
    float invE = 1.f / (float)NE;
    float mean_raw = d * invE;
    float var = fmaxf(qq * invE - mean_raw * mean_raw, 0.f);
    float sc = g[io] * rsqrtf(var + 1e-5f);
    s2[io] = sc;
    c2p[io] = b[io] - (mean_raw + b2[io]) * sc;
  }
}

// ---- repack W2*s2 (col-scaled) into MFMA B-fragment layout, fp16 ----
__global__ void repack_w2s(const float* __restrict__ W2, const float* __restrict__ s2,
                           unsigned short* __restrict__ Bp) {
  int idx = blockIdx.x * 256 + threadIdx.x;
  if (idx >= 16384) return;
  int cb = idx >> 8;
  int ks = (idx >> 6) & 3;
  int lane = idx & 63;
  int col = cb * 16 + (lane & 15);
  int kbase = ks * 32 + (lane >> 4) * 8;
  float sc = s2[col];
  unsigned short tmp[8];
#pragma unroll
  for (int j = 0; j < 8; ++j)
    tmp[j] = __half_as_ushort(__float2half(W2[(size_t)(kbase + j) * 1024 + col] * sc));
  *(uint4*)&Bp[(size_t)idx * 8] = *(uint4*)tmp;
}

// ---- layer prep: hc[n,o] = sum_i h[n,i]*c2p[i*32+o];  m[n,o] = 0 ----
__global__ __launch_bounds__(256) void layer_prep(const float* __restrict__ h,
                                                  const float* __restrict__ c2p,
                                                  float* __restrict__ hc,
                                                  float* __restrict__ m, int N) {
  __shared__ float cl[1024];
  for (int i = threadIdx.x; i < 1024; i += 256) cl[i] = c2p[i];
  __syncthreads();
  int gid = blockIdx.x * 256 + threadIdx.x;
  if (gid >= N * 32) return;
  int n = gid >> 5, o = gid & 31;
  float a = 0.f;
#pragma unroll
  for (int i = 0; i < 32; ++i) a += h[(size_t)n * 32 + i] * cl[i * 32 + o];
  hc[gid] = a;
  m[gid] = 0.f;
}

// ---- FUSED msg: recompute We-tile via MFMA and contract with h[src] on the fly.
//      block = 64 edges, 4 waves. msg[e,o] = sum_i h[src,i]*((T@W2s)[e,i*32+o]) + hc[src,o]
__global__ __launch_bounds__(256) void msg_mfma(const __half* __restrict__ T,
                                                const unsigned short* __restrict__ Bp,
                                                const float* __restrict__ h,
                                                const float* __restrict__ hc,
                                                const int* __restrict__ src,
                                                const int* __restrict__ dst,
                                                float* __restrict__ m, int E) {
  __shared__ _Float16 tl[64 * 136];  // T-tile, pitch 136 halves (16B-aligned rows)
  __shared__ float hs[64 * 36];      // h[src] gather, pitch 36 (16B-aligned)
  __shared__ float ms[64 * 36];      // msg accumulator (init = hc[src])
  int t = threadIdx.x;
  int w = t >> 6, lane = t & 63;
  int arow = lane & 15, kgrp = lane >> 4;
  int e0 = blockIdx.x * 64;
  // stage h[src] + ms=hc[src] (8 floats/thread each)
  {
    int row = t >> 2, q4 = t & 3;
    int e = e0 + row;
    bool v = e < E;
    int sn = v ? src[e] : 0;
    float4 z = {0.f, 0.f, 0.f, 0.f};
    float4 h0 = v ? *(const float4*)&h[(size_t)sn * 32 + q4 * 8] : z;
    float4 h1 = v ? *(const float4*)&h[(size_t)sn * 32 + q4 * 8 + 4] : z;
    *(float4*)&hs[row * 36 + q4 * 8] = h0;
    *(float4*)&hs[row * 36 + q4 * 8 + 4] = h1;
    float4 c0 = v ? *(const float4*)&hc[(size_t)sn * 32 + q4 * 8] : z;
    float4 c1 = v ? *(const float4*)&hc[(size_t)sn * 32 + q4 * 8 + 4] : z;
    *(float4*)&ms[row * 36 + q4 * 8] = c0;
    *(float4*)&ms[row * 36 + q4 * 8 + 4] = c1;
  }
  // stage T-tile (16B chunks; zero for invalid edges)
#pragma unroll
  for (int p = 0; p < 4; ++p) {
    int u = p * 256 + t;
    int row = u >> 4, c0 = (u & 15) * 8;
    int e = e0 + row;
    uint4 z = make_uint4(0, 0, 0, 0);
    uint4 v = (e < E) ? *(const uint4*)&T[(size_t)e * 128 + c0] : z;
    *(uint4*)&tl[row * 136 + c0] = v;
  }
  __syncthreads();
#pragma unroll
  for (int cb = 0; cb < 4; ++cb) {
    f32x4 acc[4][4];
#pragma unroll
    for (int i = 0; i < 4; ++i)
#pragma unroll
      for (int j = 0; j < 4; ++j) acc[i][j] = {0.f, 0.f, 0.f, 0.f};
#pragma unroll
    for (int ks = 0; ks < 4; ++ks) {
      f16x8 a[4];
#pragma unroll
      for (int ri = 0; ri < 4; ++ri)
        a[ri] = *(const f16x8*)&tl[(ri * 16 + arow) * 136 + ks * 32 + kgrp * 8];
#pragma unroll
      for (int ci = 0; ci < 4; ++ci) {
        int f = cb * 16 + w * 4 + ci;
        f16x8 bv = *(const f16x8*)&Bp[((size_t)(f * 4 + ks) * 64 + lane) * 8];
#pragma unroll
        for (int ri = 0; ri < 4; ++ri)
          acc[ri][ci] = __builtin_amdgcn_mfma_f32_16x16x32_f16(a[ri], bv, acc[ri][ci], 0, 0, 0);
      }
    }
    // epilogue: contract with h and accumulate into ms
#pragma unroll
    for (int ci = 0; ci < 4; ++ci) {
      int colbase = cb * 256 + w * 64 + ci * 16;
      int i = colbase >> 5;            // wave-uniform input index
      int obase = colbase & 31;        // 0 or 16
#pragma unroll
      for (int ri = 0; ri < 4; ++ri) {
#pragma unroll
        for (int q = 0; q < 4; ++q) {
          int row = ri * 16 + kgrp * 4 + q;
          float hv = hs[row * 36 + i];
          atomicAdd(&ms[row * 36 + obase + arow], hv * acc[ri][ci][q]);
        }
      }
    }
  }
  __syncthreads();
  // scatter to global m by dst
  {
    int row = t >> 2, q4 = t & 3;
    int e = e0 + row;
    if (e < E) {
      int dn = dst[e];
      float* mp = m + (size_t)dn * 32 + q4 * 8;
#pragma unroll
      for (int j = 0; j < 8; ++j) atomicAdd(&mp[j], ms[row * 36 + q4 * 8 + j]);
    }
  }
}

// ---- node embedding ----
template <int K, int COUT>
__global__ __launch_bounds__(256) void embed_gemm(const float* __restrict__ x,
                                                  const float* __restrict__ s,
                                                  const float* __restrict__ c,
                                                  const float* __restrict__ W,
                                                  const float* __restrict__ bias,
                                                  float* __restrict__ out, int R) {
  __shared__ float Wl[K * COUT];
  __shared__ float sl[K], cl[K];
  for (int i = threadIdx.x; i < K * COUT; i += 256) Wl[i] = W[i];
  for (int i = threadIdx.x; i < K; i += 256) { sl[i] = s[i]; cl[i] = c[i]; }
  __syncthreads();
  int gid = blockIdx.x * 256 + threadIdx.x;
  if (gid >= R * COUT) return;
  int r = gid / COUT, j = gid % COUT;
  float acc = bias[j];
#pragma unroll
  for (int k = 0; k < K; ++k) acc += (x[(size_t)r * K + k] * sl[k] + cl[k]) * Wl[k * COUT + j];
  out[gid] = acc;
}

// ---- GRU cell ----
__global__ __launch_bounds__(256) void gru_kernel(const float* __restrict__ m,
                                                  const float* __restrict__ inv_den,
                                                  const float* __restrict__ h_in,
                                                  const float* __restrict__ Wih,
                                                  const float* __restrict__ Whh,
                                                  const float* __restrict__ bih,
                                                  const float* __restrict__ bhh,
                                                  float* __restrict__ h_out, int N) {
  __shared__ float WT[32 * 96], UT[32 * 96];
  for (int idx = threadIdx.x; idx < 96 * 32; idx += 256) {
    int j = idx / 32, i = idx % 32;
    WT[i * 96 + j] = Wih[idx];
    UT[i * 96 + j] = Whh[idx];
  }
  __syncthreads();
  int gid = blockIdx.x * 256 + threadIdx.x;
  if (gid >= N * 32) return;
  int n = gid >> 5, o = gid & 31;
  float inv = inv_den[n];
  float air = 0.f, aiz = 0.f, ain = 0.f, ahr = 0.f, ahz = 0.f, ahn = 0.f;
#pragma unroll
  for (int i = 0; i < 32; ++i) {
    float mi = m[(size_t)n * 32 + i] * inv;
    float hi = h_in[(size_t)n * 32 + i];
    const float* w = &WT[i * 96 + o];
    const float* u = &UT[i * 96 + o];
    air += mi * w[0];  aiz += mi * w[32];  ain += mi * w[64];
    ahr += hi * u[0];  ahz += hi * u[32];  ahn += hi * u[64];
  }
  float r = 1.f / (1.f + expf(-(air + bih[o] + ahr + bhh[o])));
  float z = 1.f / (1.f + expf(-(aiz + bih[o + 32] + ahz + bhh[o + 32])));
  float ng = tanhf(ain + bih[o + 64] + r * (ahn + bhh[o + 64]));
  h_out[gid] = (1.f - z) * ng + z * h_in[(size_t)n * 32 + o];
}

extern "C" void kernel_launch(void* const* d_in, const int* in_sizes, int n_in,
                              void* d_out, int out_size, void* d_ws, size_t ws_size,
                              hipStream_t stream) {
  const float* x_node = (const float*)d_in[0];
  const float* x_edge = (const float*)d_in[1];
  const int* src = (const int*)d_in[2];
  const int* dst = (const int*)d_in[3];
  const float* bn_n_g = (const float*)d_in[4];
  const float* bn_n_b = (const float*)d_in[5];
  const float* node_W = (const float*)d_in[6];
  const float* node_b = (const float*)d_in[7];
  const float* bn_e_g = (const float*)d_in[8];
  const float* bn_e_b = (const float*)d_in[9];
  const float* edge_W = (const float*)d_in[10];
  const float* edge_b = (const float*)d_in[11];
  const float* en_W1 = (const float*)d_in[12];
  const float* en_b1 = (const float*)d_in[13];
  const float* en_bn1_g = (const float*)d_in[14];
  const float* en_bn1_b = (const float*)d_in[15];
  const float* en_W2 = (const float*)d_in[16];
  const float* en_b2 = (const float*)d_in[17];
  const float* en_bn2_g = (const float*)d_in[18];
  const float* en_bn2_b = (const float*)d_in[19];
  const float* gWih = (const float*)d_in[20];
  const float* gWhh = (const float*)d_in[21];
  const float* gbih = (const float*)d_in[22];
  const float* gbhh = (const float*)d_in[23];
  float* out = (float*)d_out;

  char* ws = (char*)d_ws;
  __half* Tt      = (__half*)(ws + 0);              // 25,600,000
  float* tsq_part = (float*)(ws + 25600000);        // 16,777,216
  float* h_a      = (float*)(ws + 42377216);        //  2,560,000
  float* h_b      = (float*)(ws + 44937216);        //  2,560,000
  float* m_buf    = (float*)(ws + 47497216);        //  2,560,000
  float* hc       = (float*)(ws + 50057216);        //  2,560,000
  float* inv_den  = (float*)(ws + 52617216);        //     80,000
  float* zbase    = (float*)(ws + 52697216);        //    147,584 (36,896 f)
  float* deg   = zbase;                             // 20000
  float* S     = zbase + 20000;                     // 16384
  float* tsum  = zbase + 36384;                     // 128
  float* sxs   = zbase + 36512;                     // 128 (110 used)
  float* nstat = zbase + 36640;                     // 128 (80 used)
  float* estat = zbase + 36768;                     // 128 (20 used)
  float* par   = (float*)(ws + 52844800);           // 4096 f
  float* ns = par + 0;    float* nc = par + 64;
  float* es = par + 128;  float* ec = par + 192;
  float* s1 = par + 256;  float* c1 = par + 384;
  float* wc = par + 512;                            // 1280 f
  float* bcb = par + 1792;                          // 128 f
  float* s2 = par + 1920; float* c2p = par + 2944;  // 1024 f each
  unsigned short* Bp = (unsigned short*)(ws + 52861184);  // 262,144 B

  zerok<<<(36896 + 255) / 256, 256, 0, stream>>>(zbase, 36896);

  colstats<40><<<200, 256, 0, stream>>>(x_node, nstat, NN * 40);
  colstats<10><<<256, 256, 0, stream>>>(x_edge, estat, NE * 10);
  deg_kernel<<<(NE + 255) / 256, 256, 0, stream>>>(dst, deg, NE);
  finalize_bn<<<1, 64, 0, stream>>>(nstat, bn_n_g, bn_n_b, ns, nc, 40, 1.f / NN);
  finalize_bn<<<1, 64, 0, stream>>>(estat, bn_e_g, bn_e_b, es, ec, 10, 1.f / NE);
  invden_kernel<<<(NN + 255) / 256, 256, 0, stream>>>(deg, inv_den, NN);

  fold_w1<<<1, 256, 0, stream>>>(edge_W, edge_b, en_W1, en_b1, wc, bcb);
  sx_kernel<<<128, 64, 0, stream>>>(x_edge, es, ec, sxs, NE);
  bn1_from_sx<<<1, 128, 0, stream>>>(sxs, wc, bcb, en_bn1_g, en_bn1_b, s1, c1);
  t_kernel<<<NE / 16, 256, 0, stream>>>(x_edge, es, ec, wc, bcb, s1, c1, Tt, NE);

  colsum_t<<<512, 256, 0, stream>>>(Tt, tsum, NE);
  tsq_mfma<<<TSQ_NB, 256, 0, stream>>>(Tt, tsq_part, NE);
  tsq_reduce<<<64, 256, 0, stream>>>(tsq_part, S);
  bn2p<<<256, 256, 0, stream>>>(S, tsum, en_W2, en_b2, en_bn2_g, en_bn2_b, s2, c2p);

  embed_gemm<40, 32><<<(NN * 32 + 255) / 256, 256, 0, stream>>>(x_node, ns, nc, node_W, node_b, h_a, NN);
  repack_w2s<<<64, 256, 0, stream>>>(en_W2, s2, Bp);

  const float* hin = h_a;
  for (int l = 0; l < 3; ++l) {
    float* hout = (l == 0) ? h_b : (l == 1) ? h_a : out;
    layer_prep<<<(NN * 32 + 255) / 256, 256, 0, stream>>>(hin, c2p, hc, m_buf, NN);
    msg_mfma<<<(NE + 63) / 64, 256, 0, stream>>>(Tt, Bp, hin, hc, src, dst, m_buf, NE);
    gru_kernel<<<(NN * 32 + 255) / 256, 256, 0, stream>>>(m_buf, inv_den, hin, gWih, gWhh,
                                                          gbih, gbhh, hout, NN);
    hin = hout;
  }
}

// Round 7
// 892.505 us; speedup vs baseline: 2.4582x; 2.4582x over previous
//
#include <hip/hip_runtime.h>
#include <hip/hip_fp16.h>

#define NN 20000
#define NE 100000
#define TSQ_NB 256

typedef _Float16 f16x8 __attribute__((ext_vector_type(8)));
typedef float f32x4 __attribute__((ext_vector_type(4)));

__device__ __forceinline__ float wred(float v) {
#pragma unroll
  for (int k = 1; k < 64; k <<= 1) v += __shfl_xor(v, k);
  return v;
}

__global__ void zerok(float* __restrict__ p, int n) {
  int i = blockIdx.x * 256 + threadIdx.x;
  if (i < n) p[i] = 0.f;
}

// ---- per-column sum / sumsq over [R, C] fp32 ----
template <int C>
__global__ void colstats(const float* __restrict__ x, float* __restrict__ stat, int total) {
  __shared__ float ls[2 * C];
  for (int i = threadIdx.x; i < 2 * C; i += blockDim.x) ls[i] = 0.f;
  __syncthreads();
  for (int idx = blockIdx.x * blockDim.x + threadIdx.x; idx < total; idx += gridDim.x * blockDim.x) {
    float v = x[idx];
    int c = idx % C;
    atomicAdd(&ls[c], v);
    atomicAdd(&ls[C + c], v * v);
  }
  __syncthreads();
  for (int i = threadIdx.x; i < 2 * C; i += blockDim.x) atomicAdd(&stat[i], ls[i]);
}

__global__ void finalize_bn(const float* __restrict__ stat, const float* __restrict__ g,
                            const float* __restrict__ b, float* __restrict__ s_out,
                            float* __restrict__ c_out, int C, float invR) {
  int c = blockIdx.x * blockDim.x + threadIdx.x;
  if (c >= C) return;
  float mean = stat[c] * invR;
  float var = fmaxf(stat[C + c] * invR - mean * mean, 0.f);
  float sc = g[c] * rsqrtf(var + 1e-5f);
  s_out[c] = sc;
  c_out[c] = b[c] - mean * sc;
}

__global__ void deg_kernel(const int* __restrict__ dst, float* __restrict__ deg, int E) {
  int e = blockIdx.x * blockDim.x + threadIdx.x;
  if (e < E) atomicAdd(&deg[dst[e]], 1.f);
}

__global__ void invden_kernel(const float* __restrict__ deg, float* __restrict__ inv, int N) {
  int n = blockIdx.x * blockDim.x + threadIdx.x;
  if (n < N) inv[n] = 1.f / fmaxf(deg[n], 1.f);
}

// ---- Wc[10,128] = edge_W @ en_W1 ; bc[128] = edge_b @ en_W1 + en_b1 ----
__global__ void fold_w1(const float* __restrict__ edge_W, const float* __restrict__ edge_b,
                        const float* __restrict__ en_W1, const float* __restrict__ en_b1,
                        float* __restrict__ Wc, float* __restrict__ bc) {
  int t = threadIdx.x;
  for (int idx = t; idx < 1280; idx += 256) {
    int bq = idx >> 7, j = idx & 127;
    float a = 0.f;
    for (int q = 0; q < 128; ++q) a += edge_W[bq * 128 + q] * en_W1[q * 128 + j];
    Wc[idx] = a;
  }
  if (t < 128) {
    float a = en_b1[t];
    for (int q = 0; q < 128; ++q) a += edge_b[q] * en_W1[q * 128 + t];
    bc[t] = a;
  }
}

// ---- Sx[10][10] + xsum[10] over xb = x*es+ec ----
__global__ __launch_bounds__(64) void sx_kernel(const float* __restrict__ x,
                                                const float* __restrict__ es,
                                                const float* __restrict__ ec,
                                                float* __restrict__ sxs, int E) {
  float s[10][10], xs[10], esl[10], ecl[10];
#pragma unroll
  for (int a = 0; a < 10; ++a) {
    xs[a] = 0.f; esl[a] = es[a]; ecl[a] = ec[a];
#pragma unroll
    for (int b = 0; b < 10; ++b) s[a][b] = 0.f;
  }
  for (int e = blockIdx.x * 64 + threadIdx.x; e < E; e += gridDim.x * 64) {
    float xb[10];
#pragma unroll
    for (int q = 0; q < 10; ++q) xb[q] = x[(size_t)e * 10 + q] * esl[q] + ecl[q];
#pragma unroll
    for (int a = 0; a < 10; ++a) {
      xs[a] += xb[a];
#pragma unroll
      for (int b = 0; b < 10; ++b) s[a][b] += xb[a] * xb[b];
    }
  }
#pragma unroll
  for (int a = 0; a < 10; ++a) {
    float r = wred(xs[a]);
    if (threadIdx.x == 0) atomicAdd(&sxs[100 + a], r);
#pragma unroll
    for (int b = 0; b < 10; ++b) {
      float r2 = wred(s[a][b]);
      if (threadIdx.x == 0) atomicAdd(&sxs[a * 10 + b], r2);
    }
  }
}

// ---- BN1 scale/shift from Sx quadratic form ----
__global__ void bn1_from_sx(const float* __restrict__ sxs, const float* __restrict__ Wc,
                            const float* __restrict__ bc, const float* __restrict__ g,
                            const float* __restrict__ b, float* __restrict__ s1,
                            float* __restrict__ c1) {
  int j = threadIdx.x;  // 128
  float w[10];
#pragma unroll
  for (int q = 0; q < 10; ++q) w[q] = Wc[q * 128 + j];
  float d = 0.f;
#pragma unroll
  for (int q = 0; q < 10; ++q) d += sxs[100 + q] * w[q];
  float qq = 0.f;
#pragma unroll
  for (int a = 0; a < 10; ++a) {
    float p = 0.f;
#pragma unroll
    for (int bq = 0; bq < 10; ++bq) p += sxs[a * 10 + bq] * w[bq];
    qq += w[a] * p;
  }
  float invE = 1.f / (float)NE;
  float bias = bc[j];
  float mean = d * invE + bias;
  float m2 = (qq + 2.f * bias * d) * invE + bias * bias;
  float var = fmaxf(m2 - mean * mean, 0.f);
  float sc = g[j] * rsqrtf(var + 1e-5f);
  s1[j] = sc;
  c1[j] = b[j] - mean * sc;
}

// ---- t[e,j] = leaky(bn1(xb@Wc + bc)) -> fp16 [NE,128]; 16 rows/block ----
__global__ __launch_bounds__(256) void t_kernel(const float* __restrict__ x,
                                                const float* __restrict__ es,
                                                const float* __restrict__ ec,
                                                const float* __restrict__ Wc,
                                                const float* __restrict__ bcb,
                                                const float* __restrict__ s1,
                                                const float* __restrict__ c1,
                                                __half* __restrict__ T, int E) {
  __shared__ float Wcl[1280], bcl[128], s1l[128], c1l[128], esl[10], ecl[10];
  __shared__ float xr[16][10];
  int t = threadIdx.x;
  for (int i = t; i < 1280; i += 256) Wcl[i] = Wc[i];
  if (t < 128) { bcl[t] = bcb[t]; s1l[t] = s1[t]; c1l[t] = c1[t]; }
  if (t < 10) { esl[t] = es[t]; ecl[t] = ec[t]; }
  int r0 = blockIdx.x * 16;
  if (t < 160) xr[t / 10][t % 10] = x[(size_t)r0 * 10 + t];
  __syncthreads();
  int rl = t >> 4, c0 = (t & 15) * 8;
  float acc[8];
#pragma unroll
  for (int j = 0; j < 8; ++j) acc[j] = bcl[c0 + j];
#pragma unroll
  for (int q = 0; q < 10; ++q) {
    float xb = xr[rl][q] * esl[q] + ecl[q];
#pragma unroll
    for (int j = 0; j < 8; ++j) acc[j] += xb * Wcl[q * 128 + c0 + j];
  }
  f16x8 o;
#pragma unroll
  for (int j = 0; j < 8; ++j) {
    float tv = acc[j] * s1l[c0 + j] + c1l[c0 + j];
    tv = tv > 0.f ? tv : 0.8f * tv;
    o[j] = (_Float16)tv;
  }
  *(f16x8*)&T[(size_t)(r0 + rl) * 128 + c0] = o;
}

// ---- tsum[128] = column sum of T ----
__global__ __launch_bounds__(256) void colsum_t(const __half* __restrict__ T,
                                                float* __restrict__ tsum, int E) {
  __shared__ float cs[128];
  int t = threadIdx.x;
  int col = t & 127, hf = t >> 7;
  float a = 0.f;
  for (int r = blockIdx.x * 2 + hf; r < E; r += gridDim.x * 2)
    a += __half2float(T[(size_t)r * 128 + col]);
  if (hf) cs[col] = a;
  __syncthreads();
  if (!hf) atomicAdd(&tsum[col], a + cs[col]);
}

// ---- MFMA S = T^T @ T: per-block 128x128 fp32 partial ----
__global__ __launch_bounds__(256) void tsq_mfma(const __half* __restrict__ T,
                                                float* __restrict__ partial, int E) {
  __shared__ _Float16 tl[32 * 132];
  int t = threadIdx.x;
  int w = t >> 6, lane = t & 63;
  int g = lane >> 4, cl = lane & 15;
  f32x4 acc[2][8];
#pragma unroll
  for (int i = 0; i < 2; ++i)
#pragma unroll
    for (int j = 0; j < 8; ++j) acc[i][j] = {0.f, 0.f, 0.f, 0.f};
  int nch = E >> 5;
  for (int ch = blockIdx.x; ch < nch; ch += gridDim.x) {
    __syncthreads();
#pragma unroll
    for (int p = 0; p < 4; ++p) {
      int u = p * 256 + t;
      int e = u >> 5, c0 = (u & 31) * 4;
      *(uint2*)&tl[e * 132 + c0] = *(const uint2*)&T[((size_t)ch * 32 + e) * 128 + c0];
    }
    __syncthreads();
    f16x8 fr[8];
#pragma unroll
    for (int cb = 0; cb < 8; ++cb) {
      f16x8 f;
#pragma unroll
      for (int j = 0; j < 8; ++j) f[j] = tl[(g * 8 + j) * 132 + cb * 16 + cl];
      fr[cb] = f;
    }
    f16x8 afr[2];
#pragma unroll
    for (int ri = 0; ri < 2; ++ri) {
      int cb = w * 2 + ri;
      f16x8 f;
#pragma unroll
      for (int j = 0; j < 8; ++j) f[j] = tl[(g * 8 + j) * 132 + cb * 16 + cl];
      afr[ri] = f;
    }
#pragma unroll
    for (int ri = 0; ri < 2; ++ri)
#pragma unroll
      for (int ci = 0; ci < 8; ++ci)
        acc[ri][ci] = __builtin_amdgcn_mfma_f32_16x16x32_f16(afr[ri], fr[ci], acc[ri][ci], 0, 0, 0);
  }
  float* pb = partial + (size_t)blockIdx.x * 16384;
#pragma unroll
  for (int ri = 0; ri < 2; ++ri)
#pragma unroll
    for (int ci = 0; ci < 8; ++ci)
#pragma unroll
      for (int q = 0; q < 4; ++q)
        pb[(w * 32 + ri * 16 + g * 4 + q) * 128 + ci * 16 + cl] = acc[ri][ci][q];
}

__global__ void tsq_reduce(const float* __restrict__ partial, float* __restrict__ S) {
  int i = blockIdx.x * 256 + threadIdx.x;  // 16384
  float a = 0.f;
  for (int b = 0; b < TSQ_NB; ++b) a += partial[(size_t)b * 16384 + i];
  S[i] = a;
}

// ---- parallel BN2 from S quadratic form ----
__global__ __launch_bounds__(256) void bn2p(const float* __restrict__ S,
                                            const float* __restrict__ tsum,
                                            const float* __restrict__ W2,
                                            const float* __restrict__ b2,
                                            const float* __restrict__ g,
                                            const float* __restrict__ b,
                                            float* __restrict__ s2, float* __restrict__ c2p) {
  __shared__ float Sl[16384];
  __shared__ float tsl[128];
  for (int i = threadIdx.x; i < 16384; i += 256) Sl[i] = S[i];
  if (threadIdx.x < 128) tsl[threadIdx.x] = tsum[threadIdx.x];
  __syncthreads();
  int w = threadIdx.x >> 6, lane = threadIdx.x & 63;
  int io = blockIdx.x * 4 + w;
  float wlo = W2[(size_t)lane * 1024 + io];
  float whi = W2[(size_t)(lane + 64) * 1024 + io];
  float plo = 0.f, phi = 0.f;
#pragma unroll
  for (int a = 0; a < 64; ++a) {
    float wa = __shfl(wlo, a);
    plo += wa * Sl[a * 128 + lane];
    phi += wa * Sl[a * 128 + lane + 64];
  }
#pragma unroll
  for (int a = 0; a < 64; ++a) {
    float wa = __shfl(whi, a);
    plo += wa * Sl[(a + 64) * 128 + lane];
    phi += wa * Sl[(a + 64) * 128 + lane + 64];
  }
  float qq = wred(plo * wlo + phi * whi);
  float d = wred(wlo * tsl[lane] + whi * tsl[lane + 64]);
  if (lane == 0) {
    float invE = 1.f / (float)NE;
    float mean_raw = d * invE;
    float var = fmaxf(qq * invE - mean_raw * mean_raw, 0.f);
    float sc = g[io] * rsqrtf(var + 1e-5f);
    s2[io] = sc;
    c2p[io] = b[io] - (mean_raw + b2[io]) * sc;
  }
}

// ---- repack W2*s2 (col-scaled) into MFMA B-fragment layout, fp16 ----
__global__ void repack_w2s(const float* __restrict__ W2, const float* __restrict__ s2,
                           unsigned short* __restrict__ Bp) {
  int idx = blockIdx.x * 256 + threadIdx.x;
  if (idx >= 16384) return;
  int cb = idx >> 8;
  int ks = (idx >> 6) & 3;
  int lane = idx & 63;
  int col = cb * 16 + (lane & 15);
  int kbase = ks * 32 + (lane >> 4) * 8;
  float sc = s2[col];
  unsigned short tmp[8];
#pragma unroll
  for (int j = 0; j < 8; ++j)
    tmp[j] = __half_as_ushort(__float2half(W2[(size_t)(kbase + j) * 1024 + col] * sc));
  *(uint4*)&Bp[(size_t)idx * 8] = *(uint4*)tmp;
}

// ---- layer prep: hc[n,o] = sum_i h[n,i]*c2p[i*32+o];  m[n,o] = 0 ----
__global__ __launch_bounds__(256) void layer_prep(const float* __restrict__ h,
                                                  const float* __restrict__ c2p,
                                                  float* __restrict__ hc,
                                                  float* __restrict__ m, int N) {
  __shared__ float cl[1024];
  for (int i = threadIdx.x; i < 1024; i += 256) cl[i] = c2p[i];
  __syncthreads();
  int gid = blockIdx.x * 256 + threadIdx.x;
  if (gid >= N * 32) return;
  int n = gid >> 5, o = gid & 31;
  float a = 0.f;
#pragma unroll
  for (int i = 0; i < 32; ++i) a += h[(size_t)n * 32 + i] * cl[i * 32 + o];
  hc[gid] = a;
  m[gid] = 0.f;
}

// ---- FUSED msg v3: MFMA recompute of We-tile + atomic-free register contraction.
//      64 edges/block, 4 waves. Wave w owns i in {8cb+2w, 8cb+2w+1}.
__global__ __launch_bounds__(256) void msg_mfma(const __half* __restrict__ T,
                                                const unsigned short* __restrict__ Bp,
                                                const float* __restrict__ h,
                                                const float* __restrict__ hc,
                                                const int* __restrict__ src,
                                                const int* __restrict__ dst,
                                                float* __restrict__ m, int E) {
  __shared__ float hst[32 * 68];     // h[src] transposed: hst[i*68 + row]
  __shared__ float msw[4 * 2208];    // per-wave partials: [w][o*69 + row]
  int t = threadIdx.x;
  int w = t >> 6, lane = t & 63;
  int arow = lane & 15, kgrp = lane >> 4;
  int e0 = blockIdx.x * 64;
  // ---- stage h[src] transposed: wave w handles i-block w*8..w*8+7, row = lane ----
  {
    int row = lane;
    int e = e0 + row;
    int sn = (e < E) ? src[e] : 0;
    float4 h0 = *(const float4*)&h[(size_t)sn * 32 + w * 8];
    float4 h1 = *(const float4*)&h[(size_t)sn * 32 + w * 8 + 4];
    hst[(w * 8 + 0) * 68 + row] = h0.x; hst[(w * 8 + 1) * 68 + row] = h0.y;
    hst[(w * 8 + 2) * 68 + row] = h0.z; hst[(w * 8 + 3) * 68 + row] = h0.w;
    hst[(w * 8 + 4) * 68 + row] = h1.x; hst[(w * 8 + 5) * 68 + row] = h1.y;
    hst[(w * 8 + 6) * 68 + row] = h1.z; hst[(w * 8 + 7) * 68 + row] = h1.w;
  }
  __syncthreads();
  // ---- MFMA + register contraction ----
  f32x4 pm[2][4];  // [o-half][ri], component = q
#pragma unroll
  for (int p = 0; p < 2; ++p)
#pragma unroll
    for (int ri = 0; ri < 4; ++ri) pm[p][ri] = {0.f, 0.f, 0.f, 0.f};
#pragma unroll
  for (int cb = 0; cb < 4; ++cb) {
    f32x4 acc[4][4];
#pragma unroll
    for (int i = 0; i < 4; ++i)
#pragma unroll
      for (int j = 0; j < 4; ++j) acc[i][j] = {0.f, 0.f, 0.f, 0.f};
#pragma unroll
    for (int ks = 0; ks < 4; ++ks) {
      f16x8 a[4];
#pragma unroll
      for (int ri = 0; ri < 4; ++ri) {
        int r = e0 + ri * 16 + arow;
        f16x8 av{};
        if (r < E) av = *(const f16x8*)&T[(size_t)r * 128 + ks * 32 + kgrp * 8];
        a[ri] = av;
      }
#pragma unroll
      for (int ci = 0; ci < 4; ++ci) {
        int f = cb * 16 + w * 4 + ci;
        f16x8 bv = *(const f16x8*)&Bp[((size_t)(f * 4 + ks) * 64 + lane) * 8];
#pragma unroll
        for (int ri = 0; ri < 4; ++ri)
          acc[ri][ci] = __builtin_amdgcn_mfma_f32_16x16x32_f16(a[ri], bv, acc[ri][ci], 0, 0, 0);
      }
    }
    // contraction: pm[ci&1][ri] += hst[i][rows] * acc[ri][ci]
#pragma unroll
    for (int ci = 0; ci < 4; ++ci) {
      int i = cb * 8 + w * 2 + (ci >> 1);
#pragma unroll
      for (int ri = 0; ri < 4; ++ri) {
        f32x4 hv = *(const f32x4*)&hst[i * 68 + ri * 16 + kgrp * 4];  // broadcast/16 lanes
        if (ci & 1) pm[1][ri] += hv * acc[ri][ci];
        else        pm[0][ri] += hv * acc[ri][ci];
      }
    }
  }
  // ---- write per-wave partials (scalar stores, pitch 69: <=2-way banks) ----
  {
    float* mw = &msw[w * 2208];
#pragma unroll
    for (int p = 0; p < 2; ++p) {
      int o = arow + 16 * p;
#pragma unroll
      for (int ri = 0; ri < 4; ++ri) {
        int rb = ri * 16 + kgrp * 4;
        mw[o * 69 + rb + 0] = pm[p][ri][0];
        mw[o * 69 + rb + 1] = pm[p][ri][1];
        mw[o * 69 + rb + 2] = pm[p][ri][2];
        mw[o * 69 + rb + 3] = pm[p][ri][3];
      }
    }
  }
  __syncthreads();
  // ---- reduce 4 waves + hc + scatter to m[dst] ----
  {
    int row = t >> 2, q4 = t & 3;
    int e = e0 + row;
    if (e < E) {
      int sn = src[e], dn = dst[e];
      float* mp = m + (size_t)dn * 32;
      const float* hcp = hc + (size_t)sn * 32;
#pragma unroll
      for (int j = 0; j < 8; ++j) {
        int o = q4 * 8 + j;
        float v = msw[0 * 2208 + o * 69 + row] + msw[1 * 2208 + o * 69 + row] +
                  msw[2 * 2208 + o * 69 + row] + msw[3 * 2208 + o * 69 + row];
        v += hcp[o];
        atomicAdd(&mp[o], v);
      }
    }
  }
}

// ---- node embedding ----
template <int K, int COUT>
__global__ __launch_bounds__(256) void embed_gemm(const float* __restrict__ x,
                                                  const float* __restrict__ s,
                                                  const float* __restrict__ c,
                                                  const float* __restrict__ W,
                                                  const float* __restrict__ bias,
                                                  float* __restrict__ out, int R) {
  __shared__ float Wl[K * COUT];
  __shared__ float sl[K], cl[K];
  for (int i = threadIdx.x; i < K * COUT; i += 256) Wl[i] = W[i];
  for (int i = threadIdx.x; i < K; i += 256) { sl[i] = s[i]; cl[i] = c[i]; }
  __syncthreads();
  int gid = blockIdx.x * 256 + threadIdx.x;
  if (gid >= R * COUT) return;
  int r = gid / COUT, j = gid % COUT;
  float acc = bias[j];
#pragma unroll
  for (int k = 0; k < K; ++k) acc += (x[(size_t)r * K + k] * sl[k] + cl[k]) * Wl[k * COUT + j];
  out[gid] = acc;
}

// ---- GRU cell ----
__global__ __launch_bounds__(256) void gru_kernel(const float* __restrict__ m,
                                                  const float* __restrict__ inv_den,
                                                  const float* __restrict__ h_in,
                                                  const float* __restrict__ Wih,
                                                  const float* __restrict__ Whh,
                                                  const float* __restrict__ bih,
                                                  const float* __restrict__ bhh,
                                                  float* __restrict__ h_out, int N) {
  __shared__ float WT[32 * 96], UT[32 * 96];
  for (int idx = threadIdx.x; idx < 96 * 32; idx += 256) {
    int j = idx / 32, i = idx % 32;
    WT[i * 96 + j] = Wih[idx];
    UT[i * 96 + j] = Whh[idx];
  }
  __syncthreads();
  int gid = blockIdx.x * 256 + threadIdx.x;
  if (gid >= N * 32) return;
  int n = gid >> 5, o = gid & 31;
  float inv = inv_den[n];
  float air = 0.f, aiz = 0.f, ain = 0.f, ahr = 0.f, ahz = 0.f, ahn = 0.f;
#pragma unroll
  for (int i = 0; i < 32; ++i) {
    float mi = m[(size_t)n * 32 + i] * inv;
    float hi = h_in[(size_t)n * 32 + i];
    const float* w = &WT[i * 96 + o];
    const float* u = &UT[i * 96 + o];
    air += mi * w[0];  aiz += mi * w[32];  ain += mi * w[64];
    ahr += hi * u[0];  ahz += hi * u[32];  ahn += hi * u[64];
  }
  float r = 1.f / (1.f + expf(-(air + bih[o] + ahr + bhh[o])));
  float z = 1.f / (1.f + expf(-(aiz + bih[o + 32] + ahz + bhh[o + 32])));
  float ng = tanhf(ain + bih[o + 64] + r * (ahn + bhh[o + 64]));
  h_out[gid] = (1.f - z) * ng + z * h_in[(size_t)n * 32 + o];
}

extern "C" void kernel_launch(void* const* d_in, const int* in_sizes, int n_in,
                              void* d_out, int out_size, void* d_ws, size_t ws_size,
                              hipStream_t stream) {
  const float* x_node = (const float*)d_in[0];
  const float* x_edge = (const float*)d_in[1];
  const int* src = (const int*)d_in[2];
  const int* dst = (const int*)d_in[3];
  const float* bn_n_g = (const float*)d_in[4];
  const float* bn_n_b = (const float*)d_in[5];
  const float* node_W = (const float*)d_in[6];
  const float* node_b = (const float*)d_in[7];
  const float* bn_e_g = (const float*)d_in[8];
  const float* bn_e_b = (const float*)d_in[9];
  const float* edge_W = (const float*)d_in[10];
  const float* edge_b = (const float*)d_in[11];
  const float* en_W1 = (const float*)d_in[12];
  const float* en_b1 = (const float*)d_in[13];
  const float* en_bn1_g = (const float*)d_in[14];
  const float* en_bn1_b = (const float*)d_in[15];
  const float* en_W2 = (const float*)d_in[16];
  const float* en_b2 = (const float*)d_in[17];
  const float* en_bn2_g = (const float*)d_in[18];
  const float* en_bn2_b = (const float*)d_in[19];
  const float* gWih = (const float*)d_in[20];
  const float* gWhh = (const float*)d_in[21];
  const float* gbih = (const float*)d_in[22];
  const float* gbhh = (const float*)d_in[23];
  float* out = (float*)d_out;

  char* ws = (char*)d_ws;
  __half* Tt      = (__half*)(ws + 0);              // 25,600,000
  float* tsq_part = (float*)(ws + 25600000);        // 16,777,216
  float* h_a      = (float*)(ws + 42377216);        //  2,560,000
  float* h_b      = (float*)(ws + 44937216);        //  2,560,000
  float* m_buf    = (float*)(ws + 47497216);        //  2,560,000
  float* hc       = (float*)(ws + 50057216);        //  2,560,000
  float* inv_den  = (float*)(ws + 52617216);        //     80,000
  float* zbase    = (float*)(ws + 52697216);        //    147,584 (36,896 f)
  float* deg   = zbase;                             // 20000
  float* S     = zbase + 20000;                     // 16384
  float* tsum  = zbase + 36384;                     // 128
  float* sxs   = zbase + 36512;
  float* nstat = zbase + 36640;
  float* estat = zbase + 36768;
  float* par   = (float*)(ws + 52844800);           // 4096 f
  float* ns = par + 0;    float* nc = par + 64;
  float* es = par + 128;  float* ec = par + 192;
  float* s1 = par + 256;  float* c1 = par + 384;
  float* wc = par + 512;                            // 1280 f
  float* bcb = par + 1792;                          // 128 f
  float* s2 = par + 1920; float* c2p = par + 2944;  // 1024 f each
  unsigned short* Bp = (unsigned short*)(ws + 52861184);  // 262,144 B

  zerok<<<(36896 + 255) / 256, 256, 0, stream>>>(zbase, 36896);

  colstats<40><<<200, 256, 0, stream>>>(x_node, nstat, NN * 40);
  colstats<10><<<256, 256, 0, stream>>>(x_edge, estat, NE * 10);
  deg_kernel<<<(NE + 255) / 256, 256, 0, stream>>>(dst, deg, NE);
  finalize_bn<<<1, 64, 0, stream>>>(nstat, bn_n_g, bn_n_b, ns, nc, 40, 1.f / NN);
  finalize_bn<<<1, 64, 0, stream>>>(estat, bn_e_g, bn_e_b, es, ec, 10, 1.f / NE);
  invden_kernel<<<(NN + 255) / 256, 256, 0, stream>>>(deg, inv_den, NN);

  fold_w1<<<1, 256, 0, stream>>>(edge_W, edge_b, en_W1, en_b1, wc, bcb);
  sx_kernel<<<128, 64, 0, stream>>>(x_edge, es, ec, sxs, NE);
  bn1_from_sx<<<1, 128, 0, stream>>>(sxs, wc, bcb, en_bn1_g, en_bn1_b, s1, c1);
  t_kernel<<<NE / 16, 256, 0, stream>>>(x_edge, es, ec, wc, bcb, s1, c1, Tt, NE);

  colsum_t<<<512, 256, 0, stream>>>(Tt, tsum, NE);
  tsq_mfma<<<TSQ_NB, 256, 0, stream>>>(Tt, tsq_part, NE);
  tsq_reduce<<<64, 256, 0, stream>>>(tsq_part, S);
  bn2p<<<256, 256, 0, stream>>>(S, tsum, en_W2, en_b2, en_bn2_g, en_bn2_b, s2, c2p);

  embed_gemm<40, 32><<<(NN * 32 + 255) / 256, 256, 0, stream>>>(x_node, ns, nc, node_W, node_b, h_a, NN);
  repack_w2s<<<64, 256, 0, stream>>>(en_W2, s2, Bp);

  const float* hin = h_a;
  for (int l = 0; l < 3; ++l) {
    float* hout = (l == 0) ? h_b : (l == 1) ? h_a : out;
    layer_prep<<<(NN * 32 + 255) / 256, 256, 0, stream>>>(hin, c2p, hc, m_buf, NN);
    msg_mfma<<<(NE + 63) / 64, 256, 0, stream>>>(Tt, Bp, hin, hc, src, dst, m_buf, NE);
    gru_kernel<<<(NN * 32 + 255) / 256, 256, 0, stream>>>(m_buf, inv_den, hin, gWih, gWhh,
                                                          gbih, gbhh, hout, NN);
    hin = hout;
  }
}

// Round 8
// 627.800 us; speedup vs baseline: 3.4947x; 1.4216x over previous
//
#include <hip/hip_runtime.h>
#include <hip/hip_fp16.h>

#define NN 20000
#define NE 100000
#define TSQ_NB 256

typedef _Float16 f16x8 __attribute__((ext_vector_type(8)));
typedef float f32x4 __attribute__((ext_vector_type(4)));

__device__ __forceinline__ float wred(float v) {
#pragma unroll
  for (int k = 1; k < 64; k <<= 1) v += __shfl_xor(v, k);
  return v;
}

__global__ void zerok(float* __restrict__ p, int n) {
  int i = blockIdx.x * 256 + threadIdx.x;
  if (i < n) p[i] = 0.f;
}

// ---- per-column sum / sumsq over [R, C] fp32 ----
template <int C>
__global__ void colstats(const float* __restrict__ x, float* __restrict__ stat, int total) {
  __shared__ float ls[2 * C];
  for (int i = threadIdx.x; i < 2 * C; i += blockDim.x) ls[i] = 0.f;
  __syncthreads();
  for (int idx = blockIdx.x * blockDim.x + threadIdx.x; idx < total; idx += gridDim.x * blockDim.x) {
    float v = x[idx];
    int c = idx % C;
    atomicAdd(&ls[c], v);
    atomicAdd(&ls[C + c], v * v);
  }
  __syncthreads();
  for (int i = threadIdx.x; i < 2 * C; i += blockDim.x) atomicAdd(&stat[i], ls[i]);
}

__global__ void finalize_bn(const float* __restrict__ stat, const float* __restrict__ g,
                            const float* __restrict__ b, float* __restrict__ s_out,
                            float* __restrict__ c_out, int C, float invR) {
  int c = blockIdx.x * blockDim.x + threadIdx.x;
  if (c >= C) return;
  float mean = stat[c] * invR;
  float var = fmaxf(stat[C + c] * invR - mean * mean, 0.f);
  float sc = g[c] * rsqrtf(var + 1e-5f);
  s_out[c] = sc;
  c_out[c] = b[c] - mean * sc;
}

__global__ void deg_kernel(const int* __restrict__ dst, float* __restrict__ deg, int E) {
  int e = blockIdx.x * blockDim.x + threadIdx.x;
  if (e < E) atomicAdd(&deg[dst[e]], 1.f);
}

__global__ void invden_kernel(const float* __restrict__ deg, float* __restrict__ inv, int N) {
  int n = blockIdx.x * blockDim.x + threadIdx.x;
  if (n < N) inv[n] = 1.f / fmaxf(deg[n], 1.f);
}

// ---- Wc[10,128] = edge_W @ en_W1 ; bc[128] = edge_b @ en_W1 + en_b1 ----
__global__ void fold_w1(const float* __restrict__ edge_W, const float* __restrict__ edge_b,
                        const float* __restrict__ en_W1, const float* __restrict__ en_b1,
                        float* __restrict__ Wc, float* __restrict__ bc) {
  int t = threadIdx.x;
  for (int idx = t; idx < 1280; idx += 256) {
    int bq = idx >> 7, j = idx & 127;
    float a = 0.f;
    for (int q = 0; q < 128; ++q) a += edge_W[bq * 128 + q] * en_W1[q * 128 + j];
    Wc[idx] = a;
  }
  if (t < 128) {
    float a = en_b1[t];
    for (int q = 0; q < 128; ++q) a += edge_b[q] * en_W1[q * 128 + t];
    bc[t] = a;
  }
}

// ---- Sx[10][10] + xsum[10] over xb = x*es+ec ----
__global__ __launch_bounds__(64) void sx_kernel(const float* __restrict__ x,
                                                const float* __restrict__ es,
                                                const float* __restrict__ ec,
                                                float* __restrict__ sxs, int E) {
  float s[10][10], xs[10], esl[10], ecl[10];
#pragma unroll
  for (int a = 0; a < 10; ++a) {
    xs[a] = 0.f; esl[a] = es[a]; ecl[a] = ec[a];
#pragma unroll
    for (int b = 0; b < 10; ++b) s[a][b] = 0.f;
  }
  for (int e = blockIdx.x * 64 + threadIdx.x; e < E; e += gridDim.x * 64) {
    float xb[10];
#pragma unroll
    for (int q = 0; q < 10; ++q) xb[q] = x[(size_t)e * 10 + q] * esl[q] + ecl[q];
#pragma unroll
    for (int a = 0; a < 10; ++a) {
      xs[a] += xb[a];
#pragma unroll
      for (int b = 0; b < 10; ++b) s[a][b] += xb[a] * xb[b];
    }
  }
#pragma unroll
  for (int a = 0; a < 10; ++a) {
    float r = wred(xs[a]);
    if (threadIdx.x == 0) atomicAdd(&sxs[100 + a], r);
#pragma unroll
    for (int b = 0; b < 10; ++b) {
      float r2 = wred(s[a][b]);
      if (threadIdx.x == 0) atomicAdd(&sxs[a * 10 + b], r2);
    }
  }
}

// ---- BN1 scale/shift from Sx quadratic form ----
__global__ void bn1_from_sx(const float* __restrict__ sxs, const float* __restrict__ Wc,
                            const float* __restrict__ bc, const float* __restrict__ g,
                            const float* __restrict__ b, float* __restrict__ s1,
                            float* __restrict__ c1) {
  int j = threadIdx.x;  // 128
  float w[10];
#pragma unroll
  for (int q = 0; q < 10; ++q) w[q] = Wc[q * 128 + j];
  float d = 0.f;
#pragma unroll
  for (int q = 0; q < 10; ++q) d += sxs[100 + q] * w[q];
  float qq = 0.f;
#pragma unroll
  for (int a = 0; a < 10; ++a) {
    float p = 0.f;
#pragma unroll
    for (int bq = 0; bq < 10; ++bq) p += sxs[a * 10 + bq] * w[bq];
    qq += w[a] * p;
  }
  float invE = 1.f / (float)NE;
  float bias = bc[j];
  float mean = d * invE + bias;
  float m2 = (qq + 2.f * bias * d) * invE + bias * bias;
  float var = fmaxf(m2 - mean * mean, 0.f);
  float sc = g[j] * rsqrtf(var + 1e-5f);
  s1[j] = sc;
  c1[j] = b[j] - mean * sc;
}

// ---- t[e,j] = leaky(bn1(xb@Wc + bc)) -> fp16 [NE,128]; 16 rows/block ----
__global__ __launch_bounds__(256) void t_kernel(const float* __restrict__ x,
                                                const float* __restrict__ es,
                                                const float* __restrict__ ec,
                                                const float* __restrict__ Wc,
                                                const float* __restrict__ bcb,
                                                const float* __restrict__ s1,
                                                const float* __restrict__ c1,
                                                __half* __restrict__ T, int E) {
  __shared__ float Wcl[1280], bcl[128], s1l[128], c1l[128], esl[10], ecl[10];
  __shared__ float xr[16][10];
  int t = threadIdx.x;
  for (int i = t; i < 1280; i += 256) Wcl[i] = Wc[i];
  if (t < 128) { bcl[t] = bcb[t]; s1l[t] = s1[t]; c1l[t] = c1[t]; }
  if (t < 10) { esl[t] = es[t]; ecl[t] = ec[t]; }
  int r0 = blockIdx.x * 16;
  if (t < 160) xr[t / 10][t % 10] = x[(size_t)r0 * 10 + t];
  __syncthreads();
  int rl = t >> 4, c0 = (t & 15) * 8;
  float acc[8];
#pragma unroll
  for (int j = 0; j < 8; ++j) acc[j] = bcl[c0 + j];
#pragma unroll
  for (int q = 0; q < 10; ++q) {
    float xb = xr[rl][q] * esl[q] + ecl[q];
#pragma unroll
    for (int j = 0; j < 8; ++j) acc[j] += xb * Wcl[q * 128 + c0 + j];
  }
  f16x8 o;
#pragma unroll
  for (int j = 0; j < 8; ++j) {
    float tv = acc[j] * s1l[c0 + j] + c1l[c0 + j];
    tv = tv > 0.f ? tv : 0.8f * tv;
    o[j] = (_Float16)tv;
  }
  *(f16x8*)&T[(size_t)(r0 + rl) * 128 + c0] = o;
}

// ---- tsum[128] = column sum of T ----
__global__ __launch_bounds__(256) void colsum_t(const __half* __restrict__ T,
                                                float* __restrict__ tsum, int E) {
  __shared__ float cs[128];
  int t = threadIdx.x;
  int col = t & 127, hf = t >> 7;
  float a = 0.f;
  for (int r = blockIdx.x * 2 + hf; r < E; r += gridDim.x * 2)
    a += __half2float(T[(size_t)r * 128 + col]);
  if (hf) cs[col] = a;
  __syncthreads();
  if (!hf) atomicAdd(&tsum[col], a + cs[col]);
}

// ---- MFMA S = T^T @ T: per-block 128x128 fp32 partial ----
__global__ __launch_bounds__(256) void tsq_mfma(const __half* __restrict__ T,
                                                float* __restrict__ partial, int E) {
  __shared__ _Float16 tl[32 * 132];
  int t = threadIdx.x;
  int w = t >> 6, lane = t & 63;
  int g = lane >> 4, cl = lane & 15;
  f32x4 acc[2][8];
#pragma unroll
  for (int i = 0; i < 2; ++i)
#pragma unroll
    for (int j = 0; j < 8; ++j) acc[i][j] = {0.f, 0.f, 0.f, 0.f};
  int nch = E >> 5;
  for (int ch = blockIdx.x; ch < nch; ch += gridDim.x) {
    __syncthreads();
#pragma unroll
    for (int p = 0; p < 4; ++p) {
      int u = p * 256 + t;
      int e = u >> 5, c0 = (u & 31) * 4;
      *(uint2*)&tl[e * 132 + c0] = *(const uint2*)&T[((size_t)ch * 32 + e) * 128 + c0];
    }
    __syncthreads();
    f16x8 fr[8];
#pragma unroll
    for (int cb = 0; cb < 8; ++cb) {
      f16x8 f;
#pragma unroll
      for (int j = 0; j < 8; ++j) f[j] = tl[(g * 8 + j) * 132 + cb * 16 + cl];
      fr[cb] = f;
    }
    f16x8 afr[2];
#pragma unroll
    for (int ri = 0; ri < 2; ++ri) {
      int cb = w * 2 + ri;
      f16x8 f;
#pragma unroll
      for (int j = 0; j < 8; ++j) f[j] = tl[(g * 8 + j) * 132 + cb * 16 + cl];
      afr[ri] = f;
    }
#pragma unroll
    for (int ri = 0; ri < 2; ++ri)
#pragma unroll
      for (int ci = 0; ci < 8; ++ci)
        acc[ri][ci] = __builtin_amdgcn_mfma_f32_16x16x32_f16(afr[ri], fr[ci], acc[ri][ci], 0, 0, 0);
  }
  float* pb = partial + (size_t)blockIdx.x * 16384;
#pragma unroll
  for (int ri = 0; ri < 2; ++ri)
#pragma unroll
    for (int ci = 0; ci < 8; ++ci)
#pragma unroll
      for (int q = 0; q < 4; ++q)
        pb[(w * 32 + ri * 16 + g * 4 + q) * 128 + ci * 16 + cl] = acc[ri][ci][q];
}

__global__ void tsq_reduce(const float* __restrict__ partial, float* __restrict__ S) {
  int i = blockIdx.x * 256 + threadIdx.x;  // 16384
  float a = 0.f;
  for (int b = 0; b < TSQ_NB; ++b) a += partial[(size_t)b * 16384 + i];
  S[i] = a;
}

// ---- parallel BN2 from S quadratic form ----
__global__ __launch_bounds__(256) void bn2p(const float* __restrict__ S,
                                            const float* __restrict__ tsum,
                                            const float* __restrict__ W2,
                                            const float* __restrict__ b2,
                                            const float* __restrict__ g,
                                            const float* __restrict__ b,
                                            float* __restrict__ s2, float* __restrict__ c2p) {
  __shared__ float Sl[16384];
  __shared__ float tsl[128];
  for (int i = threadIdx.x; i < 16384; i += 256) Sl[i] = S[i];
  if (threadIdx.x < 128) tsl[threadIdx.x] = tsum[threadIdx.x];
  __syncthreads();
  int w = threadIdx.x >> 6, lane = threadIdx.x & 63;
  int io = blockIdx.x * 4 + w;
  float wlo = W2[(size_t)lane * 1024 + io];
  float whi = W2[(size_t)(lane + 64) * 1024 + io];
  float plo = 0.f, phi = 0.f;
#pragma unroll
  for (int a = 0; a < 64; ++a) {
    float wa = __shfl(wlo, a);
    plo += wa * Sl[a * 128 + lane];
    phi += wa * Sl[a * 128 + lane + 64];
  }
#pragma unroll
  for (int a = 0; a < 64; ++a) {
    float wa = __shfl(whi, a);
    plo += wa * Sl[(a + 64) * 128 + lane];
    phi += wa * Sl[(a + 64) * 128 + lane + 64];
  }
  float qq = wred(plo * wlo + phi * whi);
  float d = wred(wlo * tsl[lane] + whi * tsl[lane + 64]);
  if (lane == 0) {
    float invE = 1.f / (float)NE;
    float mean_raw = d * invE;
    float var = fmaxf(qq * invE - mean_raw * mean_raw, 0.f);
    float sc = g[io] * rsqrtf(var + 1e-5f);
    s2[io] = sc;
    c2p[io] = b[io] - (mean_raw + b2[io]) * sc;
  }
}

// ---- repack W2*s2 (col-scaled) into MFMA B-fragment layout, fp16 ----
__global__ void repack_w2s(const float* __restrict__ W2, const float* __restrict__ s2,
                           unsigned short* __restrict__ Bp) {
  int idx = blockIdx.x * 256 + threadIdx.x;
  if (idx >= 16384) return;
  int cb = idx >> 8;
  int ks = (idx >> 6) & 3;
  int lane = idx & 63;
  int col = cb * 16 + (lane & 15);
  int kbase = ks * 32 + (lane >> 4) * 8;
  float sc = s2[col];
  unsigned short tmp[8];
#pragma unroll
  for (int j = 0; j < 8; ++j)
    tmp[j] = __half_as_ushort(__float2half(W2[(size_t)(kbase + j) * 1024 + col] * sc));
  *(uint4*)&Bp[(size_t)idx * 8] = *(uint4*)tmp;
}

// ---- layer prep: hc[n,o] = sum_i h[n,i]*c2p[i*32+o];  m[n,o] = 0 ----
__global__ __launch_bounds__(256) void layer_prep(const float* __restrict__ h,
                                                  const float* __restrict__ c2p,
                                                  float* __restrict__ hc,
                                                  float* __restrict__ m, int N) {
  __shared__ float cl[1024];
  for (int i = threadIdx.x; i < 1024; i += 256) cl[i] = c2p[i];
  __syncthreads();
  int gid = blockIdx.x * 256 + threadIdx.x;
  if (gid >= N * 32) return;
  int n = gid >> 5, o = gid & 31;
  float a = 0.f;
#pragma unroll
  for (int i = 0; i < 32; ++i) a += h[(size_t)n * 32 + i] * cl[i * 32 + o];
  hc[gid] = a;
  m[gid] = 0.f;
}

// ---- FUSED msg v4: 32 edges/block, low-VGPR re-tile of v3.
//      acc[2][4], pm[2][2], A hoisted once (ah[4][2]). ----
__global__ __launch_bounds__(256, 3) void msg_mfma(const __half* __restrict__ T,
                                                   const unsigned short* __restrict__ Bp,
                                                   const float* __restrict__ h,
                                                   const float* __restrict__ hc,
                                                   const int* __restrict__ src,
                                                   const int* __restrict__ dst,
                                                   float* __restrict__ m, int E) {
  __shared__ float hst[32 * 36];     // hst[i*36 + row]; pitch 36 keeps b128 16B-aligned
  __shared__ float msw[4 * 1056];    // per-wave partials: [w][o*33 + row]
  int t = threadIdx.x;
  int w = t >> 6, lane = t & 63;
  int arow = lane & 15, kgrp = lane >> 4;
  int e0 = blockIdx.x * 32;
  // ---- stage h[src] transposed: hst[i][row] = h[src[e0+row]][i] ----
  {
    int row = t >> 3, i0 = (t & 7) * 4;
    int e = e0 + row;
    int sn = (e < E) ? src[e] : 0;
    float4 hv = *(const float4*)&h[(size_t)sn * 32 + i0];
    hst[(i0 + 0) * 36 + row] = hv.x;
    hst[(i0 + 1) * 36 + row] = hv.y;
    hst[(i0 + 2) * 36 + row] = hv.z;
    hst[(i0 + 3) * 36 + row] = hv.w;
  }
  __syncthreads();
  // ---- A fragments hoisted once: ah[ks][ri] ----
  f16x8 ah[4][2];
#pragma unroll
  for (int ks = 0; ks < 4; ++ks)
#pragma unroll
    for (int ri = 0; ri < 2; ++ri) {
      int r = e0 + ri * 16 + arow;
      f16x8 av{};
      if (r < E) av = *(const f16x8*)&T[(size_t)r * 128 + ks * 32 + kgrp * 8];
      ah[ks][ri] = av;
    }
  f32x4 pm[2][2];
#pragma unroll
  for (int p = 0; p < 2; ++p)
#pragma unroll
    for (int ri = 0; ri < 2; ++ri) pm[p][ri] = {0.f, 0.f, 0.f, 0.f};
#pragma unroll
  for (int cb = 0; cb < 4; ++cb) {
    f32x4 acc[2][4];
#pragma unroll
    for (int i = 0; i < 2; ++i)
#pragma unroll
      for (int j = 0; j < 4; ++j) acc[i][j] = {0.f, 0.f, 0.f, 0.f};
#pragma unroll
    for (int ks = 0; ks < 4; ++ks) {
#pragma unroll
      for (int ci = 0; ci < 4; ++ci) {
        int f = cb * 16 + w * 4 + ci;
        f16x8 bv = *(const f16x8*)&Bp[((size_t)(f * 4 + ks) * 64 + lane) * 8];
        acc[0][ci] = __builtin_amdgcn_mfma_f32_16x16x32_f16(ah[ks][0], bv, acc[0][ci], 0, 0, 0);
        acc[1][ci] = __builtin_amdgcn_mfma_f32_16x16x32_f16(ah[ks][1], bv, acc[1][ci], 0, 0, 0);
      }
    }
    // contraction: pm[ci&1][ri] += hst[i][rows] * acc[ri][ci]
#pragma unroll
    for (int ci = 0; ci < 4; ++ci) {
      int i = cb * 8 + w * 2 + (ci >> 1);
#pragma unroll
      for (int ri = 0; ri < 2; ++ri) {
        f32x4 hv = *(const f32x4*)&hst[i * 36 + ri * 16 + kgrp * 4];
        if (ci & 1) pm[1][ri] += hv * acc[ri][ci];
        else        pm[0][ri] += hv * acc[ri][ci];
      }
    }
  }
  // ---- write per-wave partials ----
  {
    float* mw = &msw[w * 1056];
#pragma unroll
    for (int p = 0; p < 2; ++p) {
      int o = p * 16 + arow;
#pragma unroll
      for (int ri = 0; ri < 2; ++ri) {
        int rb = ri * 16 + kgrp * 4;
        mw[o * 33 + rb + 0] = pm[p][ri][0];
        mw[o * 33 + rb + 1] = pm[p][ri][1];
        mw[o * 33 + rb + 2] = pm[p][ri][2];
        mw[o * 33 + rb + 3] = pm[p][ri][3];
      }
    }
  }
  __syncthreads();
  // ---- reduce 4 waves + hc + scatter to m[dst] ----
  {
    int row = t >> 3, o0 = (t & 7) * 4;
    int e = e0 + row;
    if (e < E) {
      int sn = src[e], dn = dst[e];
      float* mp = m + (size_t)dn * 32;
      const float* hcp = hc + (size_t)sn * 32;
#pragma unroll
      for (int j = 0; j < 4; ++j) {
        int o = o0 + j;
        float v = msw[0 * 1056 + o * 33 + row] + msw[1 * 1056 + o * 33 + row] +
                  msw[2 * 1056 + o * 33 + row] + msw[3 * 1056 + o * 33 + row];
        v += hcp[o];
        atomicAdd(&mp[o], v);
      }
    }
  }
}

// ---- node embedding ----
template <int K, int COUT>
__global__ __launch_bounds__(256) void embed_gemm(const float* __restrict__ x,
                                                  const float* __restrict__ s,
                                                  const float* __restrict__ c,
                                                  const float* __restrict__ W,
                                                  const float* __restrict__ bias,
                                                  float* __restrict__ out, int R) {
  __shared__ float Wl[K * COUT];
  __shared__ float sl[K], cl[K];
  for (int i = threadIdx.x; i < K * COUT; i += 256) Wl[i] = W[i];
  for (int i = threadIdx.x; i < K; i += 256) { sl[i] = s[i]; cl[i] = c[i]; }
  __syncthreads();
  int gid = blockIdx.x * 256 + threadIdx.x;
  if (gid >= R * COUT) return;
  int r = gid / COUT, j = gid % COUT;
  float acc = bias[j];
#pragma unroll
  for (int k = 0; k < K; ++k) acc += (x[(size_t)r * K + k] * sl[k] + cl[k]) * Wl[k * COUT + j];
  out[gid] = acc;
}

// ---- GRU cell ----
__global__ __launch_bounds__(256) void gru_kernel(const float* __restrict__ m,
                                                  const float* __restrict__ inv_den,
                                                  const float* __restrict__ h_in,
                                                  const float* __restrict__ Wih,
                                                  const float* __restrict__ Whh,
                                                  const float* __restrict__ bih,
                                                  const float* __restrict__ bhh,
                                                  float* __restrict__ h_out, int N) {
  __shared__ float WT[32 * 96], UT[32 * 96];
  for (int idx = threadIdx.x; idx < 96 * 32; idx += 256) {
    int j = idx / 32, i = idx % 32;
    WT[i * 96 + j] = Wih[idx];
    UT[i * 96 + j] = Whh[idx];
  }
  __syncthreads();
  int gid = blockIdx.x * 256 + threadIdx.x;
  if (gid >= N * 32) return;
  int n = gid >> 5, o = gid & 31;
  float inv = inv_den[n];
  float air = 0.f, aiz = 0.f, ain = 0.f, ahr = 0.f, ahz = 0.f, ahn = 0.f;
#pragma unroll
  for (int i = 0; i < 32; ++i) {
    float mi = m[(size_t)n * 32 + i] * inv;
    float hi = h_in[(size_t)n * 32 + i];
    const float* w = &WT[i * 96 + o];
    const float* u = &UT[i * 96 + o];
    air += mi * w[0];  aiz += mi * w[32];  ain += mi * w[64];
    ahr += hi * u[0];  ahz += hi * u[32];  ahn += hi * u[64];
  }
  float r = 1.f / (1.f + expf(-(air + bih[o] + ahr + bhh[o])));
  float z = 1.f / (1.f + expf(-(aiz + bih[o + 32] + ahz + bhh[o + 32])));
  float ng = tanhf(ain + bih[o + 64] + r * (ahn + bhh[o + 64]));
  h_out[gid] = (1.f - z) * ng + z * h_in[(size_t)n * 32 + o];
}

extern "C" void kernel_launch(void* const* d_in, const int* in_sizes, int n_in,
                              void* d_out, int out_size, void* d_ws, size_t ws_size,
                              hipStream_t stream) {
  const float* x_node = (const float*)d_in[0];
  const float* x_edge = (const float*)d_in[1];
  const int* src = (const int*)d_in[2];
  const int* dst = (const int*)d_in[3];
  const float* bn_n_g = (const float*)d_in[4];
  const float* bn_n_b = (const float*)d_in[5];
  const float* node_W = (const float*)d_in[6];
  const float* node_b = (const float*)d_in[7];
  const float* bn_e_g = (const float*)d_in[8];
  const float* bn_e_b = (const float*)d_in[9];
  const float* edge_W = (const float*)d_in[10];
  const float* edge_b = (const float*)d_in[11];
  const float* en_W1 = (const float*)d_in[12];
  const float* en_b1 = (const float*)d_in[13];
  const float* en_bn1_g = (const float*)d_in[14];
  const float* en_bn1_b = (const float*)d_in[15];
  const float* en_W2 = (const float*)d_in[16];
  const float* en_b2 = (const float*)d_in[17];
  const float* en_bn2_g = (const float*)d_in[18];
  const float* en_bn2_b = (const float*)d_in[19];
  const float* gWih = (const float*)d_in[20];
  const float* gWhh = (const float*)d_in[21];
  const float* gbih = (const float*)d_in[22];
  const float* gbhh = (const float*)d_in[23];
  float* out = (float*)d_out;

  char* ws = (char*)d_ws;
  __half* Tt      = (__half*)(ws + 0);              // 25,600,000
  float* tsq_part = (float*)(ws + 25600000);        // 16,777,216
  float* h_a      = (float*)(ws + 42377216);        //  2,560,000
  float* h_b      = (float*)(ws + 44937216);        //  2,560,000
  float* m_buf    = (float*)(ws + 47497216);        //  2,560,000
  float* hc       = (float*)(ws + 50057216);        //  2,560,000
  float* inv_den  = (float*)(ws + 52617216);        //     80,000
  float* zbase    = (float*)(ws + 52697216);        //    147,584 (36,896 f)
  float* deg   = zbase;                             // 20000
  float* S     = zbase + 20000;                     // 16384
  float* tsum  = zbase + 36384;                     // 128
  float* sxs   = zbase + 36512;
  float* nstat = zbase + 36640;
  float* estat = zbase + 36768;
  float* par   = (float*)(ws + 52844800);           // 4096 f
  float* ns = par + 0;    float* nc = par + 64;
  float* es = par + 128;  float* ec = par + 192;
  float* s1 = par + 256;  float* c1 = par + 384;
  float* wc = par + 512;                            // 1280 f
  float* bcb = par + 1792;                          // 128 f
  float* s2 = par + 1920; float* c2p = par + 2944;  // 1024 f each
  unsigned short* Bp = (unsigned short*)(ws + 52861184);  // 262,144 B

  zerok<<<(36896 + 255) / 256, 256, 0, stream>>>(zbase, 36896);

  colstats<40><<<200, 256, 0, stream>>>(x_node, nstat, NN * 40);
  colstats<10><<<256, 256, 0, stream>>>(x_edge, estat, NE * 10);
  deg_kernel<<<(NE + 255) / 256, 256, 0, stream>>>(dst, deg, NE);
  finalize_bn<<<1, 64, 0, stream>>>(nstat, bn_n_g, bn_n_b, ns, nc, 40, 1.f / NN);
  finalize_bn<<<1, 64, 0, stream>>>(estat, bn_e_g, bn_e_b, es, ec, 10, 1.f / NE);
  invden_kernel<<<(NN + 255) / 256, 256, 0, stream>>>(deg, inv_den, NN);

  fold_w1<<<1, 256, 0, stream>>>(edge_W, edge_b, en_W1, en_b1, wc, bcb);
  sx_kernel<<<128, 64, 0, stream>>>(x_edge, es, ec, sxs, NE);
  bn1_from_sx<<<1, 128, 0, stream>>>(sxs, wc, bcb, en_bn1_g, en_bn1_b, s1, c1);
  t_kernel<<<NE / 16, 256, 0, stream>>>(x_edge, es, ec, wc, bcb, s1, c1, Tt, NE);

  colsum_t<<<512, 256, 0, stream>>>(Tt, tsum, NE);
  tsq_mfma<<<TSQ_NB, 256, 0, stream>>>(Tt, tsq_part, NE);
  tsq_reduce<<<64, 256, 0, stream>>>(tsq_part, S);
  bn2p<<<256, 256, 0, stream>>>(S, tsum, en_W2, en_b2, en_bn2_g, en_bn2_b, s2, c2p);

  embed_gemm<40, 32><<<(NN * 32 + 255) / 256, 256, 0, stream>>>(x_node, ns, nc, node_W, node_b, h_a, NN);
  repack_w2s<<<64, 256, 0, stream>>>(en_W2, s2, Bp);

  const float* hin = h_a;
  for (int l = 0; l < 3; ++l) {
    float* hout = (l == 0) ? h_b : (l == 1) ? h_a : out;
    layer_prep<<<(NN * 32 + 255) / 256, 256, 0, stream>>>(hin, c2p, hc, m_buf, NN);
    msg_mfma<<<(NE + 31) / 32, 256, 0, stream>>>(Tt, Bp, hin, hc, src, dst, m_buf, NE);
    gru_kernel<<<(NN * 32 + 255) / 256, 256, 0, stream>>>(m_buf, inv_den, hin, gWih, gWhh,
                                                          gbih, gbhh, hout, NN);
    hin = hout;
  }
}